// Round 1
// baseline (1971.395 us; speedup 1.0000x reference)
//
#include <hip/hip_runtime.h>
#include <math.h>

// Problem constants (fixed by setup_inputs: B=8, n=256, s=256)
#define NCTRL 256          // control points
#define NA    259          // n + 3 (TPS system size)
#define APITCH 264         // padded row pitch (floats) for the augmented matrix
#define BATCH 8
#define SGRID 256

// ---------------------------------------------------------------------------
// Kernel 1: build the augmented TPS system per batch.
// A is NA x APITCH row-major. Cols 0..258 = L, col 259/260 = rhs (dst x/y),
// cols 261..263 = zero pad. Rows 0..255: [K | 1 sx sy | dstx dsty],
// rows 256..258: [P^T | 0 | 0].
// ---------------------------------------------------------------------------
template<typename T>
__global__ __launch_bounds__(256) void build_kernel(const float* __restrict__ src,
                                                    const float* __restrict__ dst,
                                                    T* __restrict__ A){
  const int b = blockIdx.x;
  const float* sb = src + b*NCTRL*2;
  const float* db = dst + b*NCTRL*2;
  T* Ab = A + (size_t)b*NA*APITCH;
  __shared__ float sx[NCTRL], sy[NCTRL];
  {
    int t = threadIdx.x;           // blockDim == 256 == NCTRL
    sx[t] = sb[2*t]; sy[t] = sb[2*t+1];
  }
  __syncthreads();
  const int total = NA*APITCH;
  for (int idx = threadIdx.x; idx < total; idx += 256){
    int r = idx / APITCH;
    int c = idx - r*APITCH;
    T v = (T)0;
    if (r < NCTRL){
      if (c < NCTRL){
        double dx = (double)sx[r] - (double)sx[c];
        double dy = (double)sy[r] - (double)sy[c];
        v = (T)sqrt(dx*dx + dy*dy);      // K(r,c) = |src_r - src_c|
      } else if (c == NCTRL)   v = (T)1;
      else if (c == NCTRL+1)   v = (T)sx[r];
      else if (c == NCTRL+2)   v = (T)sy[r];
      else if (c == NA)        v = (T)db[2*r];     // rhs x
      else if (c == NA+1)      v = (T)db[2*r+1];   // rhs y
    } else if (c < NCTRL){
      v = (r == NCTRL) ? (T)1 : ((r == NCTRL+1) ? (T)sx[c] : (T)sy[c]);
    }
    Ab[idx] = v;
  }
}

// ---------------------------------------------------------------------------
// Kernel 2: in-place Gaussian elimination with partial pivoting on the
// augmented matrix (forward elimination applied to rhs columns too), then
// back substitution. One block per batch. Pivoting is mandatory: K has a
// zero diagonal, so A[0][0] == 0.
// ---------------------------------------------------------------------------
template<typename T>
__global__ __launch_bounds__(1024) void lu_kernel(T* __restrict__ A, T* __restrict__ wv){
  const int b = blockIdx.x;
  T* Ab = A + (size_t)b*NA*APITCH;
  const int tid  = threadIdx.x;
  const int lane = tid & 63;
  const int wid  = tid >> 6;
  const int nwaves = blockDim.x >> 6;   // 16

  __shared__ T pivrow[NA+2];            // staged pivot row, cols k..260 at [j-k]
  __shared__ T flds[NA];                // elimination factors by absolute row
  __shared__ float redv[16];
  __shared__ int   redi[16];
  __shared__ T bx[NA], by[NA];          // back-substitution vectors

  for (int k = 0; k < NA-1; ++k){
    // --- 1. partial pivot search: argmax |A[i][k]|, i in [k, NA) ---
    float bestv = -1.0f; int besti = k;
    for (int i = k + tid; i < NA; i += blockDim.x){
      float av = fabsf((float)Ab[i*APITCH + k]);
      if (av > bestv){ bestv = av; besti = i; }
    }
    for (int off = 32; off; off >>= 1){
      float ov = __shfl_xor(bestv, off);
      int   oi = __shfl_xor(besti, off);
      if (ov > bestv || (ov == bestv && oi < besti)){ bestv = ov; besti = oi; }
    }
    if (lane == 0){ redv[wid] = bestv; redi[wid] = besti; }
    __syncthreads();                                   // B1
    float bv = redv[0]; int p = redi[0];
    for (int w = 1; w < nwaves; ++w){
      if (redv[w] > bv || (redv[w] == bv && redi[w] < p)){ bv = redv[w]; p = redi[w]; }
    }
    // --- 2. swap rows k<->p over cols [k, 260] and stage pivot row in LDS ---
    // (cols < k are dead after their step since rhs is augmented)
    for (int j = k + tid; j <= NA+1; j += blockDim.x){
      T ak = Ab[k*APITCH + j];
      T ap = Ab[p*APITCH + j];
      if (p != k){ Ab[k*APITCH + j] = ap; Ab[p*APITCH + j] = ak; }
      pivrow[j - k] = (p != k) ? ap : ak;
    }
    __syncthreads();                                   // B2
    const T rpiv = (T)1 / pivrow[0];
    // --- 3. factors ---
    for (int i = k + 1 + tid; i < NA; i += blockDim.x){
      flds[i] = Ab[i*APITCH + k] * rpiv;
    }
    __syncthreads();                                   // B3
    // --- 4. trailing update, wave-per-row, lanes over consecutive cols ---
    for (int i = k + 1 + wid; i < NA; i += nwaves){
      const T f = flds[i];
      T* row = Ab + (size_t)i*APITCH;
      for (int j = k + 1 + lane; j <= NA+1; j += 64){
        row[j] -= f * pivrow[j - k];
      }
    }
    __syncthreads();                                   // B4
  }

  // --- back substitution (2 rhs channels) ---
  for (int i = tid; i < NA; i += blockDim.x){
    bx[i] = Ab[i*APITCH + NA];
    by[i] = Ab[i*APITCH + NA+1];
  }
  __syncthreads();
  for (int k = NA-1; k >= 0; --k){
    if (tid == 0){
      T d = Ab[k*APITCH + k];
      bx[k] /= d; by[k] /= d;
    }
    __syncthreads();
    const T xk = bx[k], yk = by[k];
    for (int i = tid; i < k; i += blockDim.x){
      T a = Ab[i*APITCH + k];
      bx[i] -= a * xk;
      by[i] -= a * yk;
    }
    __syncthreads();
  }
  for (int i = tid; i < NA; i += blockDim.x){
    wv[(b*NA + i)*2 + 0] = bx[i];
    wv[(b*NA + i)*2 + 1] = by[i];
  }
}

// ---------------------------------------------------------------------------
// Kernel 3: evaluate the warp on the s x s grid.
// Block = one output row (256 pixels), grid = B * s blocks.
// out[b][c][yi][xi], grid point: x = lin[xi], y = lin[yi].
// ---------------------------------------------------------------------------
template<typename T>
__global__ __launch_bounds__(256) void eval_kernel(const float* __restrict__ src,
                                                   const T* __restrict__ wv,
                                                   float* __restrict__ out){
  const int b  = blockIdx.x >> 8;
  const int yi = blockIdx.x & 255;
  const int xi = threadIdx.x;
  __shared__ float sx[NCTRL], sy[NCTRL], wx[NCTRL], wy[NCTRL];
  const float* sb = src + b*NCTRL*2;
  const T* wb = wv + (size_t)b*NA*2;
  sx[xi] = sb[2*xi]; sy[xi] = sb[2*xi+1];
  wx[xi] = (float)wb[2*xi]; wy[xi] = (float)wb[2*xi+1];
  __syncthreads();

  const float step = 2.0f/255.0f;
  const float gx = -1.0f + step*(float)xi;
  const float gy = -1.0f + step*(float)yi;

  // affine part: wv rows 256 (const), 257 (gx), 258 (gy)
  float accx = (float)wb[512] + (float)wb[514]*gx + (float)wb[516]*gy;
  float accy = (float)wb[513] + (float)wb[515]*gx + (float)wb[517]*gy;

  for (int j = 0; j < NCTRL; ++j){
    float dx = gx - sx[j];
    float dy = gy - sy[j];
    float r = sqrtf(fmaf(dx, dx, dy*dy));
    accx = fmaf(r, wx[j], accx);
    accy = fmaf(r, wy[j], accy);
  }
  out[((size_t)(b*2    )*SGRID + yi)*SGRID + xi] = accx;
  out[((size_t)(b*2 + 1)*SGRID + yi)*SGRID + xi] = accy;
}

// ---------------------------------------------------------------------------
extern "C" void kernel_launch(void* const* d_in, const int* in_sizes, int n_in,
                              void* d_out, int out_size, void* d_ws, size_t ws_size,
                              hipStream_t stream) {
  const float* src = (const float*)d_in[0];
  const float* dst = (const float*)d_in[1];
  float* out = (float*)d_out;

  // workspace: augmented matrices + solved weights (f32 path: ~2.2 MB)
  const size_t matElems = (size_t)BATCH*NA*APITCH;
  float* A  = (float*)d_ws;
  float* wv = A + matElems;

  build_kernel<float><<<BATCH, 256, 0, stream>>>(src, dst, A);
  lu_kernel<float><<<BATCH, 1024, 0, stream>>>(A, wv);
  eval_kernel<float><<<BATCH*SGRID, 256, 0, stream>>>(src, wv, out);
}

// Round 2
// 811.764 us; speedup vs baseline: 2.4285x; 2.4285x over previous
//
#include <hip/hip_runtime.h>
#include <math.h>

// Problem constants (fixed by setup_inputs: B=8, n=256, s=256)
#define NCTRL 256          // control points
#define NA    259          // n + 3 (TPS system size)
#define NAUG  261          // + 2 rhs columns
#define APITCH 264         // padded row pitch (floats) for the augmented matrix
#define BATCH 8
#define SGRID 256
#define NB    32           // LU panel width
#define NPAN  9            // ceil(259/32): 8 full panels + 1 of width 3
#define SPITCH 232         // LDS stage pitch (>= max trailing cols 229)

// ---------------------------------------------------------------------------
// Kernel 1: build the augmented TPS system per batch (unchanged from r1).
// ---------------------------------------------------------------------------
__global__ __launch_bounds__(256) void build_kernel(const float* __restrict__ src,
                                                    const float* __restrict__ dst,
                                                    float* __restrict__ A){
  const int b = blockIdx.x;
  const float* sb = src + b*NCTRL*2;
  const float* db = dst + b*NCTRL*2;
  float* Ab = A + (size_t)b*NA*APITCH;
  __shared__ float sx[NCTRL], sy[NCTRL];
  {
    int t = threadIdx.x;
    sx[t] = sb[2*t]; sy[t] = sb[2*t+1];
  }
  __syncthreads();
  const int total = NA*APITCH;
  for (int idx = threadIdx.x; idx < total; idx += 256){
    int r = idx / APITCH;
    int c = idx - r*APITCH;
    float v = 0.0f;
    if (r < NCTRL){
      if (c < NCTRL){
        float dx = sx[r] - sx[c];
        float dy = sy[r] - sy[c];
        v = sqrtf(fmaf(dx, dx, dy*dy));
      } else if (c == NCTRL)   v = 1.0f;
      else if (c == NCTRL+1)   v = sx[r];
      else if (c == NCTRL+2)   v = sy[r];
      else if (c == NA)        v = db[2*r];
      else if (c == NA+1)      v = db[2*r+1];
    } else if (c < NCTRL){
      v = (r == NCTRL) ? 1.0f : ((r == NCTRL+1) ? sx[c] : sy[c]);
    }
    Ab[idx] = v;
  }
}

// ---------------------------------------------------------------------------
// Kernel 2: blocked right-looking LU with partial pivoting (LAPACK getrf
// structure), one block per batch, 512 threads.
//   per panel: LDS panel factor -> laswp (gather) -> TRSM (unrolled, regs)
//              -> GEMM rank-32 update (4x4 reg tiles)
// then blocked back-substitution (2 rhs channels).
// ---------------------------------------------------------------------------
__global__ __launch_bounds__(512) void lu_blocked(float* __restrict__ A,
                                                  float* __restrict__ wv){
  const int b = blockIdx.x;
  float* Ab = A + (size_t)b*NA*APITCH;
  const int tid  = threadIdx.x;
  const int lane = tid & 63;
  const int wid  = tid >> 6;

  __shared__ float pan[NA][NB+1];      // panel / U11 stage: 259*33*4 = 34.2 KB
  __shared__ float stg[2*NB][SPITCH];  // laswp stage + U12: 64*232*4 = 59.4 KB
  __shared__ float xs2[NA*2];          // back-sub solution (x,y interleaved)
  __shared__ float tsum[NB][2];
  __shared__ int   perm[NA];
  __shared__ int   pivloc[NB];
  __shared__ int   mvlist[2*NB];
  __shared__ int   mvcnt;

  // ======================== factorization ========================
  for (int p = 0; p < NPAN; ++p){
    const int k0   = p*NB;
    const int nb   = (NA - k0 < NB) ? (NA - k0) : NB;
    const int rows = NA - k0;
    const int ctop = k0 + nb;          // first trailing column
    const int tc   = NAUG - ctop;      // trailing cols incl 2 rhs

    // --- load panel into LDS ---
    for (int idx = tid; idx < rows*nb; idx += 512){
      int i = idx / nb, j = idx - i*nb;
      pan[i][j] = Ab[(size_t)(k0+i)*APITCH + k0 + j];
    }
    if (tid == 0) mvcnt = 0;
    __syncthreads();

    // --- panel factorization: nb mini-steps, 2 barriers each ---
    for (int j = 0; j < nb; ++j){
      if (wid == 0){
        // pivot search over LDS column j, rows [j, rows)
        float bv = -1.0f; int bi = j;
        for (int i = j + lane; i < rows; i += 64){
          float a = fabsf(pan[i][j]);
          if (a > bv){ bv = a; bi = i; }
        }
        #pragma unroll
        for (int off = 32; off; off >>= 1){
          float ov = __shfl_xor(bv, off);
          int   oi = __shfl_xor(bi, off);
          if (ov > bv || (ov == bv && oi < bi)){ bv = ov; bi = oi; }
        }
        if (lane == 0) pivloc[j] = bi;
        if (bi != j && lane < nb){   // swap full panel rows j <-> bi
          float t = pan[j][lane]; pan[j][lane] = pan[bi][lane]; pan[bi][lane] = t;
        }
      }
      __syncthreads();
      // fused scale + rank-1 update; lane-pair (even,odd) per row
      const float piv = pan[j][j];
      for (int r = j + 1 + (tid >> 1); r < rows; r += 256){
        float f = pan[r][j] / piv;     // read happens lockstep before write
        if ((tid & 1) == 0) pan[r][j] = f;
        for (int c = j + 1 + (tid & 1); c < nb; c += 2)
          pan[r][c] -= f * pan[j][c];
      }
      __syncthreads();
    }

    // --- write back U11 block (rows 0..nb-1, panel cols) for back-sub ---
    for (int idx = tid; idx < nb*nb; idx += 512){
      int r = idx / nb, c = idx - r*nb;
      Ab[(size_t)(k0+r)*APITCH + k0 + c] = pan[r][c];
    }
    // --- compose row permutation of this panel ---
    for (int i = tid; i < rows; i += 512) perm[i] = i;
    __syncthreads();
    if (tid == 0){
      for (int j = 0; j < nb; ++j){
        int pj = pivloc[j];
        int t = perm[j]; perm[j] = perm[pj]; perm[pj] = t;
      }
    }
    __syncthreads();
    for (int i = tid; i < rows; i += 512)
      if (perm[i] != i){ int s = atomicAdd(&mvcnt, 1); mvlist[s] = i; }
    __syncthreads();

    // --- laswp: permute trailing cols of moved rows (gather via LDS) ---
    const int M = mvcnt;               // <= 64
    if (tc > 0 && M > 0){
      for (int idx = tid; idx < M*tc; idx += 512){
        int m = idx / tc, c = idx - m*tc;
        stg[m][c] = Ab[(size_t)(k0 + perm[mvlist[m]])*APITCH + ctop + c];
      }
      __syncthreads();
      for (int idx = tid; idx < M*tc; idx += 512){
        int m = idx / tc, c = idx - m*tc;
        Ab[(size_t)(k0 + mvlist[m])*APITCH + ctop + c] = stg[m][c];
      }
      __syncthreads();
    }

    // --- TRSM: U12 = L11^{-1} A12, thread-per-column, static unroll ---
    if (tc > 0){
      if (nb == NB){
        for (int c = tid; c < tc; c += 512){
          float u[NB];
          #pragma unroll
          for (int m = 0; m < NB; ++m) u[m] = Ab[(size_t)(k0+m)*APITCH + ctop + c];
          #pragma unroll
          for (int m = 0; m < NB; ++m){
            #pragma unroll
            for (int jj = m+1; jj < NB; ++jj)
              u[jj] -= pan[jj][m] * u[m];
          }
          #pragma unroll
          for (int m = 0; m < NB; ++m){
            Ab[(size_t)(k0+m)*APITCH + ctop + c] = u[m];
            stg[m][c] = u[m];
          }
        }
      } else {                         // nb == 3 tail panel
        for (int c = tid; c < tc; c += 512){
          float u0 = Ab[(size_t)(k0+0)*APITCH + ctop + c];
          float u1 = Ab[(size_t)(k0+1)*APITCH + ctop + c];
          float u2 = Ab[(size_t)(k0+2)*APITCH + ctop + c];
          u1 -= pan[1][0]*u0;
          u2 -= pan[2][0]*u0;
          u2 -= pan[2][1]*u1;
          Ab[(size_t)(k0+0)*APITCH + ctop + c] = u0;
          Ab[(size_t)(k0+1)*APITCH + ctop + c] = u1;
          Ab[(size_t)(k0+2)*APITCH + ctop + c] = u2;
        }
      }
      __syncthreads();
    }

    // --- GEMM: A22 -= L21 * U12, 4x4 register tiles ---
    const int R = rows - nb;
    if (R > 0 && tc > 0){
      const int rt = (R + 3) >> 2, ct = (tc + 3) >> 2;
      for (int t = tid; t < rt*ct; t += 512){
        int tr  = t / ct, tcc = t - tr*ct;
        int i0  = nb + tr*4;           // panel-local row of tile top
        int c0  = tcc*4;               // trailing-col offset of tile left
        float acc[4][4] = {};
        const bool full = (c0 + 4 <= tc);
        #pragma unroll
        for (int r = 0; r < 4; ++r){
          int i = i0 + r;
          if (i < rows){
            const float* g = Ab + (size_t)(k0+i)*APITCH + ctop + c0;
            if (full){
              float4 v = *(const float4*)g;
              acc[r][0]=v.x; acc[r][1]=v.y; acc[r][2]=v.z; acc[r][3]=v.w;
            } else {
              #pragma unroll
              for (int c = 0; c < 4; ++c)
                if (c0 + c < tc) acc[r][c] = g[c];
            }
          }
        }
        #pragma unroll
        for (int m = 0; m < NB; ++m){
          float4 uv = *(const float4*)&stg[m][c0];
          #pragma unroll
          for (int r = 0; r < 4; ++r){
            int ir = i0 + r; ir = (ir < rows) ? ir : (rows-1);
            float l = pan[ir][m];
            acc[r][0] -= l*uv.x; acc[r][1] -= l*uv.y;
            acc[r][2] -= l*uv.z; acc[r][3] -= l*uv.w;
          }
        }
        #pragma unroll
        for (int r = 0; r < 4; ++r){
          int i = i0 + r;
          if (i < rows){
            float* g = Ab + (size_t)(k0+i)*APITCH + ctop + c0;
            if (full){
              float4 v; v.x=acc[r][0]; v.y=acc[r][1]; v.z=acc[r][2]; v.w=acc[r][3];
              *(float4*)g = v;
            } else {
              #pragma unroll
              for (int c = 0; c < 4; ++c)
                if (c0 + c < tc) g[c] = acc[r][c];
            }
          }
        }
      }
      __syncthreads();
    }
  }

  // ======================== blocked back-substitution ========================
  for (int bp = NPAN-1; bp >= 0; --bp){
    const int k0 = bp*NB;
    const int nb = (NA - k0 < NB) ? (NA - k0) : NB;
    const int cs = k0 + nb;            // first already-solved row below
    const int below = NA - cs;

    // t[row][ch] = y[row][ch] - U[row, cs:] . x[cs:]   (8 threads per (row,ch))
    {
      int g = tid >> 3, sub = tid & 7;
      int row = g >> 1, ch = g & 1;
      float s = 0.0f;
      if (row < nb){
        const size_t rbase = (size_t)(k0+row)*APITCH;
        if (sub == 0) s = Ab[rbase + NA + ch];
        for (int c = sub; c < below; c += 8)
          s -= Ab[rbase + cs + c] * xs2[(cs + c)*2 + ch];
      }
      s += __shfl_xor(s, 4); s += __shfl_xor(s, 2); s += __shfl_xor(s, 1);
      if (row < nb && (sub == 0)) tsum[row][ch] = s;
    }
    // stage U11 block
    for (int idx = tid; idx < nb*nb; idx += 512){
      int r = idx / nb, c = idx - r*nb;
      pan[r][c] = Ab[(size_t)(k0+r)*APITCH + k0 + c];
    }
    __syncthreads();
    // 32x32 (or 3x3) triangular solve by wave 0: lane = row*2 + channel
    if (wid == 0){
      int j = lane >> 1, ch = lane & 1;
      float tval = (j < nb) ? tsum[j][ch] : 0.0f;
      for (int k = nb-1; k >= 0; --k){
        float tk = __shfl(tval, 2*k + ch);
        float xk = tk / pan[k][k];
        if (j <  k) tval -= pan[j][k] * xk;
        if (j == k) tval = xk;
      }
      if (j < nb) xs2[(k0+j)*2 + ch] = tval;
    }
    __syncthreads();
  }

  for (int i = tid; i < NA; i += 512){
    wv[((size_t)b*NA + i)*2 + 0] = xs2[i*2+0];
    wv[((size_t)b*NA + i)*2 + 1] = xs2[i*2+1];
  }
}

// ---------------------------------------------------------------------------
// Kernel 3: evaluate the warp on the s x s grid (unchanged from r1).
// ---------------------------------------------------------------------------
__global__ __launch_bounds__(256) void eval_kernel(const float* __restrict__ src,
                                                   const float* __restrict__ wv,
                                                   float* __restrict__ out){
  const int b  = blockIdx.x >> 8;
  const int yi = blockIdx.x & 255;
  const int xi = threadIdx.x;
  __shared__ float sx[NCTRL], sy[NCTRL], wx[NCTRL], wy[NCTRL];
  const float* sb = src + b*NCTRL*2;
  const float* wb = wv + (size_t)b*NA*2;
  sx[xi] = sb[2*xi]; sy[xi] = sb[2*xi+1];
  wx[xi] = wb[2*xi]; wy[xi] = wb[2*xi+1];
  __syncthreads();

  const float step = 2.0f/255.0f;
  const float gx = -1.0f + step*(float)xi;
  const float gy = -1.0f + step*(float)yi;

  float accx = wb[512] + wb[514]*gx + wb[516]*gy;
  float accy = wb[513] + wb[515]*gx + wb[517]*gy;

  for (int j = 0; j < NCTRL; ++j){
    float dx = gx - sx[j];
    float dy = gy - sy[j];
    float r = sqrtf(fmaf(dx, dx, dy*dy));
    accx = fmaf(r, wx[j], accx);
    accy = fmaf(r, wy[j], accy);
  }
  out[((size_t)(b*2    )*SGRID + yi)*SGRID + xi] = accx;
  out[((size_t)(b*2 + 1)*SGRID + yi)*SGRID + xi] = accy;
}

// ---------------------------------------------------------------------------
extern "C" void kernel_launch(void* const* d_in, const int* in_sizes, int n_in,
                              void* d_out, int out_size, void* d_ws, size_t ws_size,
                              hipStream_t stream) {
  const float* src = (const float*)d_in[0];
  const float* dst = (const float*)d_in[1];
  float* out = (float*)d_out;

  const size_t matElems = (size_t)BATCH*NA*APITCH;
  float* A  = (float*)d_ws;
  float* wv = A + matElems;

  build_kernel<<<BATCH, 256, 0, stream>>>(src, dst, A);
  lu_blocked<<<BATCH, 512, 0, stream>>>(A, wv);
  eval_kernel<<<BATCH*SGRID, 256, 0, stream>>>(src, wv, out);
}